// Round 1
// baseline (249.371 us; speedup 1.0000x reference)
//
#include <hip/hip_runtime.h>
#include <math.h>

#define G   50
#define T   24
#define B   128
#define NLP (B * T)
#define SZ  (B * G * T)   // 153600 elements per (B,G,T) output

// d_out layout (floats, concatenated in return order):
//   [0,      SZ)        P_DA   (B,G,T)
//   [SZ,     2SZ)       R_up
//   [2SZ,    3SZ)       R_dn
//   [3SZ,    3SZ+B)     obj    (B,)
//   [3SZ+B,  4SZ+B)     Cost_DA

__global__ __launch_bounds__(256)
void pdhg_lp_kernel(const float* __restrict__ forecast,
                    const float* __restrict__ pmin,
                    const float* __restrict__ pmax,
                    const float* __restrict__ bcost,
                    const float* __restrict__ ccost,
                    const int*   __restrict__ n_iters_p,
                    float* __restrict__ out,
                    float tau)
{
    const int lane = threadIdx.x & 63;
    const int lp   = blockIdx.x * 4 + (threadIdx.x >> 6);   // grid sized exactly
    const int b    = lp / T;
    const int t    = lp - b * T;
    const int n_iters = n_iters_p[0];

    const bool  active = (lane < G);
    const float bj  = active ? bcost[lane] : 0.f;
    const float cj  = active ? ccost[lane] : 0.f;
    const float pmx = active ? pmax[lane]  : 0.f;
    const float pmn = active ? pmin[lane]  : 0.f;
    const float f   = forecast[lp];

    const float sigma = tau;
    const float cP  = bj;           // c_obj for P
    const float cRu = 0.05f * bj;   // RES_UP_RATIO * b
    const float cRd = 0.02f * bj;   // RES_DN_RATIO * b
    const float req = 0.02f * f;    // REQ_UP_RATIO = REQ_DN_RATIO = 0.02

    // primal x = (P, Ru, Rd), dual y = (y0; y1..y4 per-gen; yru; yrd)
    float P = 0.f, Ru = 0.f, Rd = 0.f;
    float y1 = 0.f, y2 = 0.f, y3 = 0.f, y4 = 0.f;
    float y0 = 0.f, yru = 0.f, yrd = 0.f;   // wave-uniform scalars

    for (int it = 0; it < n_iters; ++it) {
        // ---- x-update: x_new = max(x - tau*(c + K^T y), 0) ----
        float gP  = cP  + y0 + y1 - y2 + y3 - y4;
        float gRu = cRu + y1 - yru;
        float gRd = cRd + y2 - yrd;
        float Pn  = fmaxf(P  - tau * gP , 0.f);
        float Run = fmaxf(Ru - tau * gRu, 0.f);
        float Rdn = fmaxf(Rd - tau * gRd, 0.f);
        if (!active) { Pn = 0.f; Run = 0.f; Rdn = 0.f; }

        // overrelaxation: x_bar = 2*x_new - x_old
        float Pb  = 2.f * Pn  - P;
        float Rub = 2.f * Run - Ru;
        float Rdb = 2.f * Rdn - Rd;
        P = Pn; Ru = Run; Rd = Rdn;

        // ---- wave reductions: S_P, S_Ru, S_Rd (3 interleaved butterflies) ----
        float sP = Pb, sRu = Rub, sRd = Rdb;
        #pragma unroll
        for (int off = 32; off > 0; off >>= 1) {
            sP  += __shfl_xor(sP , off, 64);
            sRu += __shfl_xor(sRu, off, 64);
            sRd += __shfl_xor(sRd, off, 64);
        }

        // ---- y-update: y += sigma*(K x_bar - q), clamp ineq rows ----
        y0  = y0 + sigma * (sP - f);                          // equality, no clamp
        y1  = fmaxf(y1  + sigma * ( Pb + Rub - pmx), 0.f);    // P+Ru <= pmax
        y2  = fmaxf(y2  + sigma * (-Pb + Rdb + pmn), 0.f);    // -P+Rd <= -pmin
        y3  = fmaxf(y3  + sigma * ( Pb - pmx      ), 0.f);    // P <= pmax
        y4  = fmaxf(y4  + sigma * (-Pb + pmn      ), 0.f);    // -P <= -pmin
        yru = fmaxf(yru + sigma * (req - sRu      ), 0.f);    // -sum Ru <= -req
        yrd = fmaxf(yrd + sigma * (req - sRd      ), 0.f);    // -sum Rd <= -req
    }

    if (active) {
        const int base = b * (G * T) + lane * T + t;   // (B,G,T) index
        out[base]               = P;                   // P_DA
        out[SZ + base]          = Ru;                  // R_up
        out[2 * SZ + base]      = Rd;                  // R_dn
        out[3 * SZ + B + base]  = bj * P + cj;         // Cost_DA
    }
}

// obj[b] = sum_{g,t} Cost_DA + 0.05*b_g*R_up + 0.02*b_g*R_dn  (one block per b)
__global__ __launch_bounds__(256)
void obj_kernel(const float* __restrict__ bcost, float* __restrict__ out)
{
    const int b = blockIdx.x;
    const float* Pp = out + (size_t)b * (G * T);          // unused, kept for clarity
    const float* Ru = out + SZ     + (size_t)b * (G * T);
    const float* Rd = out + 2 * SZ + (size_t)b * (G * T);
    const float* C  = out + 3 * SZ + B + (size_t)b * (G * T);
    (void)Pp;

    float s = 0.f;
    for (int i = threadIdx.x; i < G * T; i += 256) {
        const int g = i / T;
        const float bg = bcost[g];
        s += C[i] + 0.05f * bg * Ru[i] + 0.02f * bg * Rd[i];
    }
    __shared__ float sm[4];
    #pragma unroll
    for (int off = 32; off > 0; off >>= 1) s += __shfl_xor(s, off, 64);
    if ((threadIdx.x & 63) == 0) sm[threadIdx.x >> 6] = s;
    __syncthreads();
    if (threadIdx.x == 0) out[3 * SZ + b] = (sm[0] + sm[1]) + (sm[2] + sm[3]);
}

extern "C" void kernel_launch(void* const* d_in, const int* in_sizes, int n_in,
                              void* d_out, int out_size, void* d_ws, size_t ws_size,
                              hipStream_t stream) {
    const float* forecast = (const float*)d_in[0];
    const float* pmin_p   = (const float*)d_in[1];
    const float* pmax_p   = (const float*)d_in[2];
    const float* b_p      = (const float*)d_in[3];
    const float* c_p      = (const float*)d_in[4];
    const int*   niter_p  = (const int*)  d_in[5];
    float* out = (float*)d_out;

    // ||K||_2 analytic for this fixed 0/±1 structure (G=50):
    // K^T K = [[4I+J, I, -I],[I, I+J, 0],[-I, 0, I+J]]; largest eig on the
    // ones-subspace is (105+sqrt(17))/2  ->  L = sqrt((105+sqrt(17))/2)
    const double L = sqrt((105.0 + sqrt(17.0)) * 0.5);
    const float tau = (float)(0.9 / L);   // sigma == tau

    pdhg_lp_kernel<<<NLP / 4, 256, 0, stream>>>(forecast, pmin_p, pmax_p,
                                                b_p, c_p, niter_p, out, tau);
    obj_kernel<<<B, 256, 0, stream>>>(b_p, out);
}

// Round 2
// 184.985 us; speedup vs baseline: 1.3481x; 1.3481x over previous
//
#include <hip/hip_runtime.h>
#include <math.h>

#define G   50
#define T   24
#define B   128
#define NLP (B * T)
#define SZ  (B * G * T)   // 153600 elements per (B,G,T) output

// d_out layout (floats, concatenated in return order):
//   [0,      SZ)        P_DA   (B,G,T)
//   [SZ,     2SZ)       R_up
//   [2SZ,    3SZ)       R_dn
//   [3SZ,    3SZ+B)     obj    (B,)
//   [3SZ+B,  4SZ+B)     Cost_DA

// ---- DPP wave-64 sum (canonical GCN sequence, pure VALU, no LDS) ----
// update_dpp(old=0, src, ctrl, row_mask, bank_mask, bound_ctrl=true):
//   enabled+valid -> src[srclane]; enabled+invalid -> 0; masked-off row -> old(=0)
template <int CTRL, int RM>
__device__ __forceinline__ float dpp_mov(float x) {
    int r = __builtin_amdgcn_update_dpp(0, __float_as_int(x), CTRL, RM, 0xf, true);
    return __int_as_float(r);
}

// Three interleaved full-wave sums; results broadcast to all lanes via readlane.
__device__ __forceinline__ void wave_sum3(float& a, float& b, float& c) {
    a += dpp_mov<0x111, 0xf>(a); b += dpp_mov<0x111, 0xf>(b); c += dpp_mov<0x111, 0xf>(c); // row_shr:1
    a += dpp_mov<0x112, 0xf>(a); b += dpp_mov<0x112, 0xf>(b); c += dpp_mov<0x112, 0xf>(c); // row_shr:2
    a += dpp_mov<0x114, 0xf>(a); b += dpp_mov<0x114, 0xf>(b); c += dpp_mov<0x114, 0xf>(c); // row_shr:4
    a += dpp_mov<0x118, 0xf>(a); b += dpp_mov<0x118, 0xf>(b); c += dpp_mov<0x118, 0xf>(c); // row_shr:8
    a += dpp_mov<0x142, 0xa>(a); b += dpp_mov<0x142, 0xa>(b); c += dpp_mov<0x142, 0xa>(c); // row_bcast:15
    a += dpp_mov<0x143, 0xc>(a); b += dpp_mov<0x143, 0xc>(b); c += dpp_mov<0x143, 0xc>(c); // row_bcast:31
    a = __int_as_float(__builtin_amdgcn_readlane(__float_as_int(a), 63));
    b = __int_as_float(__builtin_amdgcn_readlane(__float_as_int(b), 63));
    c = __int_as_float(__builtin_amdgcn_readlane(__float_as_int(c), 63));
}

__device__ __forceinline__ float wave_sum1(float a) {
    a += dpp_mov<0x111, 0xf>(a);
    a += dpp_mov<0x112, 0xf>(a);
    a += dpp_mov<0x114, 0xf>(a);
    a += dpp_mov<0x118, 0xf>(a);
    a += dpp_mov<0x142, 0xa>(a);
    a += dpp_mov<0x143, 0xc>(a);
    return __int_as_float(__builtin_amdgcn_readlane(__float_as_int(a), 63));
}

__global__ __launch_bounds__(256)
void pdhg_lp_kernel(const float* __restrict__ forecast,
                    const float* __restrict__ pmin,
                    const float* __restrict__ pmax,
                    const float* __restrict__ bcost,
                    const float* __restrict__ ccost,
                    const int*   __restrict__ n_iters_p,
                    float* __restrict__ out,
                    float* __restrict__ ws_partial,   // NLP floats (or null)
                    float tau)
{
    const int lane = threadIdx.x & 63;
    const int lp   = blockIdx.x * 4 + (threadIdx.x >> 6);   // grid sized exactly
    const int b    = lp / T;
    const int t    = lp - b * T;
    const int n_iters = n_iters_p[0];

    const bool  active = (lane < G);
    const float bj  = active ? bcost[lane] : 0.f;
    const float cj  = active ? ccost[lane] : 0.f;
    const float pmx = active ? pmax[lane]  : 0.f;
    const float pmn = active ? pmin[lane]  : 0.f;
    const float f   = forecast[lp];

    // scaled duals: z = tau * y  (sigma == tau), ts = tau*sigma
    const float ts   = tau * tau;
    const float tcP  = tau * bj;             // tau * c_obj(P)
    const float tcRu = tau * 0.05f * bj;     // tau * RES_UP_RATIO*b
    const float tcRd = tau * 0.02f * bj;     // tau * RES_DN_RATIO*b
    const float tsf   = ts * f;
    const float tspmx = ts * pmx;
    const float tspmn = ts * pmn;
    const float tsreq = ts * 0.02f * f;      // ts * REQ_*_RATIO * forecast

    float P = 0.f, Ru = 0.f, Rd = 0.f;
    float z1 = 0.f, z2 = 0.f, z3 = 0.f, z4 = 0.f;   // per-gen scaled duals
    float z0 = 0.f, zru = 0.f, zrd = 0.f;           // wave-uniform scaled duals

    for (int it = 0; it < n_iters; ++it) {
        // ---- x-update: x_new = max(x - (tau*c + z-combination), 0) ----
        float gP  = z0 + z1 - z2 + z3 - z4;
        float Pn  = fmaxf(P  - tcP  - gP,          0.f);
        float Run = fmaxf(Ru - tcRu - (z1 - zru),  0.f);
        float Rdn = fmaxf(Rd - tcRd - (z2 - zrd),  0.f);
        if (!active) { Pn = 0.f; Run = 0.f; Rdn = 0.f; }

        // overrelaxation: x_bar = 2*x_new - x_old
        float Pb  = 2.f * Pn  - P;
        float Rub = 2.f * Run - Ru;
        float Rdb = 2.f * Rdn - Rd;
        P = Pn; Ru = Run; Rd = Rdn;

        // ---- wave-uniform sums over generators (DPP, pure VALU) ----
        float sP = Pb, sRu = Rub, sRd = Rdb;
        wave_sum3(sP, sRu, sRd);

        // ---- z-update: z += ts*(K x_bar - q), clamp ineq rows ----
        z0  = z0 + ts * sP - tsf;                              // equality row
        z1  = fmaxf(z1 + ts * (Pb + Rub) - tspmx, 0.f);        // P+Ru <= pmax
        z2  = fmaxf(z2 + ts * (Rdb - Pb) + tspmn, 0.f);        // -P+Rd <= -pmin
        z3  = fmaxf(z3 + ts * Pb - tspmx,         0.f);        // P <= pmax
        z4  = fmaxf(z4 - ts * Pb + tspmn,         0.f);        // -P <= -pmin
        zru = fmaxf(zru + tsreq - ts * sRu,       0.f);        // -sum Ru <= -req
        zrd = fmaxf(zrd + tsreq - ts * sRd,       0.f);        // -sum Rd <= -req
    }

    const float cost = bj * P + cj;
    if (active) {
        const int base = b * (G * T) + lane * T + t;   // (B,G,T) index
        out[base]               = P;                   // P_DA
        out[SZ + base]          = Ru;                  // R_up
        out[2 * SZ + base]      = Rd;                  // R_dn
        out[3 * SZ + B + base]  = cost;                // Cost_DA
    }

    if (ws_partial) {
        // per-(b,t) objective partial: sum_g cost + 0.05*b*Ru + 0.02*b*Rd
        float loc = active ? (cost + 0.05f * bj * Ru + 0.02f * bj * Rd) : 0.f;
        float tot = wave_sum1(loc);
        if (lane == 0) ws_partial[lp] = tot;
    }
}

// obj[b] = sum_t ws_partial[b*T + t]   (deterministic, tiny)
__global__ __launch_bounds__(64)
void obj_final_kernel(const float* __restrict__ ws_partial, float* __restrict__ out)
{
    const int b = blockIdx.x * 64 + threadIdx.x;
    if (b < B) {
        float s = 0.f;
        #pragma unroll
        for (int t = 0; t < T; ++t) s += ws_partial[b * T + t];
        out[3 * SZ + b] = s;
    }
}

// Fallback (ws too small): recompute obj from outputs, one block per b
__global__ __launch_bounds__(256)
void obj_kernel(const float* __restrict__ bcost, float* __restrict__ out)
{
    const int b = blockIdx.x;
    const float* Ru = out + SZ     + (size_t)b * (G * T);
    const float* Rd = out + 2 * SZ + (size_t)b * (G * T);
    const float* C  = out + 3 * SZ + B + (size_t)b * (G * T);

    float s = 0.f;
    for (int i = threadIdx.x; i < G * T; i += 256) {
        const int g = i / T;
        const float bg = bcost[g];
        s += C[i] + 0.05f * bg * Ru[i] + 0.02f * bg * Rd[i];
    }
    __shared__ float sm[4];
    s = wave_sum1(s);
    if ((threadIdx.x & 63) == 0) sm[threadIdx.x >> 6] = s;
    __syncthreads();
    if (threadIdx.x == 0) out[3 * SZ + b] = (sm[0] + sm[1]) + (sm[2] + sm[3]);
}

extern "C" void kernel_launch(void* const* d_in, const int* in_sizes, int n_in,
                              void* d_out, int out_size, void* d_ws, size_t ws_size,
                              hipStream_t stream) {
    const float* forecast = (const float*)d_in[0];
    const float* pmin_p   = (const float*)d_in[1];
    const float* pmax_p   = (const float*)d_in[2];
    const float* b_p      = (const float*)d_in[3];
    const float* c_p      = (const float*)d_in[4];
    const int*   niter_p  = (const int*)  d_in[5];
    float* out = (float*)d_out;

    // ||K||_2 analytic for this fixed 0/±1 structure (G=50):
    // K^T K = [[4I+J, I, -I],[I, I+J, 0],[-I, 0, I+J]]; largest eig on the
    // ones-subspace is (105+sqrt(17))/2  ->  L = sqrt((105+sqrt(17))/2)
    const double L = sqrt((105.0 + sqrt(17.0)) * 0.5);
    const float tau = (float)(0.9 / L);   // sigma == tau

    const bool use_ws = (ws_size >= (size_t)NLP * sizeof(float));
    float* wsp = use_ws ? (float*)d_ws : nullptr;

    pdhg_lp_kernel<<<NLP / 4, 256, 0, stream>>>(forecast, pmin_p, pmax_p,
                                                b_p, c_p, niter_p, out, wsp, tau);
    if (use_ws) {
        obj_final_kernel<<<(B + 63) / 64, 64, 0, stream>>>(wsp, out);
    } else {
        obj_kernel<<<B, 256, 0, stream>>>(b_p, out);
    }
}

// Round 3
// 147.152 us; speedup vs baseline: 1.6946x; 1.2571x over previous
//
#include <hip/hip_runtime.h>
#include <math.h>

#define G   50
#define T   24
#define B   128
#define NLP (B * T)
#define SZ  (B * G * T)   // 153600 elements per (B,G,T) output

typedef float v2f __attribute__((ext_vector_type(2)));

// d_out layout (floats, concatenated in return order):
//   [0,      SZ)        P_DA   (B,G,T)
//   [SZ,     2SZ)       R_up
//   [2SZ,    3SZ)       R_dn
//   [3SZ,    3SZ+B)     obj    (B,)
//   [3SZ+B,  4SZ+B)     Cost_DA

__device__ __forceinline__ v2f vmax0(v2f v) {
    v2f z = {0.f, 0.f};
    return __builtin_elementwise_max(v, z);
}

// DPP helper: result = src lane per CTRL (row ops), all rows/banks enabled.
template <int CTRL>
__device__ __forceinline__ float dpp_mov(float x) {
    int r = __builtin_amdgcn_update_dpp(0, __float_as_int(x), CTRL, 0xf, 0xf, true);
    return __int_as_float(r);
}

// lane ^ 16 within each 32-lane group (BitMode: xor=16, and=0x1F)
__device__ __forceinline__ float swz_xor16(float x) {
    return __int_as_float(__builtin_amdgcn_ds_swizzle(__float_as_int(x), 0x401F));
}

// All-reduce 3 values within each 32-lane HALF independently:
// 4 x row_ror (rotate-reduce within rows of 16, result in all lanes) +
// ds_swizzle lane^16 to fold the two rows of each half.
__device__ __forceinline__ void half_sum3(float& a, float& b, float& c) {
    a += dpp_mov<0x121>(a); b += dpp_mov<0x121>(b); c += dpp_mov<0x121>(c); // ror:1
    a += dpp_mov<0x122>(a); b += dpp_mov<0x122>(b); c += dpp_mov<0x122>(c); // ror:2
    a += dpp_mov<0x124>(a); b += dpp_mov<0x124>(b); c += dpp_mov<0x124>(c); // ror:4
    a += dpp_mov<0x128>(a); b += dpp_mov<0x128>(b); c += dpp_mov<0x128>(c); // ror:8
    a += swz_xor16(a);      b += swz_xor16(b);      c += swz_xor16(c);      // row0<->row1
}

__device__ __forceinline__ float half_sum1(float a) {
    a += dpp_mov<0x121>(a);
    a += dpp_mov<0x122>(a);
    a += dpp_mov<0x124>(a);
    a += dpp_mov<0x128>(a);
    a += swz_xor16(a);
    return a;
}

// Full 64-lane sum broadcast (fallback obj kernel only).
__device__ __forceinline__ float wave_sum1(float a) {
    a += dpp_mov<0x121>(a);
    a += dpp_mov<0x122>(a);
    a += dpp_mov<0x124>(a);
    a += dpp_mov<0x128>(a);
    a += swz_xor16(a);  // every lane has its 32-half sum
    // fold halves via readlane(0) + readlane(32)
    float lo = __int_as_float(__builtin_amdgcn_readlane(__float_as_int(a), 0));
    float hi = __int_as_float(__builtin_amdgcn_readlane(__float_as_int(a), 32));
    return lo + hi;
}

// One wave per block; lanes 0-31 solve LP (2*blockIdx), lanes 32-63 solve
// LP (2*blockIdx+1). Each lane owns generators lh and lh+32 packed as v2f.
__global__ __launch_bounds__(64)
void pdhg_lp_kernel(const float* __restrict__ forecast,
                    const float* __restrict__ pmin,
                    const float* __restrict__ pmax,
                    const float* __restrict__ bcost,
                    const float* __restrict__ ccost,
                    const int*   __restrict__ n_iters_p,
                    float* __restrict__ out,
                    float* __restrict__ ws_partial,   // NLP floats (or null)
                    float tau)
{
    const int lane = threadIdx.x;         // 0..63
    const int lh   = lane & 31;           // lane within half
    const int half = lane >> 5;
    const int lp   = blockIdx.x * 2 + half;
    const int b    = lp / T;
    const int t    = lp - b * T;
    const int n_iters = n_iters_p[0];

    const int  g0 = lh;                   // always < 50
    const int  g1 = lh + 32;
    const bool a1 = (g1 < G);

    v2f bj  = { bcost[g0], a1 ? bcost[g1] : 0.f };
    v2f cj  = { ccost[g0], a1 ? ccost[g1] : 0.f };
    v2f pmx = { pmax[g0],  a1 ? pmax[g1]  : 0.f };
    v2f pmn = { pmin[g0],  a1 ? pmin[g1]  : 0.f };
    const float f = forecast[lp];         // uniform within each half

    const float ts  = tau * tau;          // sigma == tau
    const float BIG = 1e30f;              // sentinel: clamps invalid slots to 0

    v2f tcP  = tau * bj;          if (!a1) tcP.y  = BIG;
    v2f tcRu = (tau * 0.05f) * bj; if (!a1) tcRu.y = BIG;
    v2f tcRd = (tau * 0.02f) * bj; if (!a1) tcRd.y = BIG;
    v2f tspmx = ts * pmx;
    v2f tspmn = ts * pmn;
    const float tsf   = ts * f;
    const float tsreq = ts * 0.02f * f;   // REQ_UP_RATIO == REQ_DN_RATIO

    v2f P = {0,0}, Ru = {0,0}, Rd = {0,0};
    v2f z1 = {0,0}, z2 = {0,0}, z3 = {0,0}, z4 = {0,0};  // scaled duals (tau*y)
    float z0 = 0.f, zru = 0.f, zrd = 0.f;                // per-half uniform

    for (int it = 0; it < n_iters; ++it) {
        // ---- x-update: x_new = max(x - (tau*c + tau*K^T y), 0) ----
        v2f gP = (z1 - z2) + (z3 - z4) + z0;
        v2f Pn = vmax0(P - tcP - gP);
        v2f Run = vmax0(Ru - tcRu - (z1 - zru));
        v2f Rdn = vmax0(Rd - tcRd - (z2 - zrd));

        // overrelaxation: x_bar = 2*x_new - x_old
        v2f Pb  = 2.f * Pn  - P;
        v2f Rub = 2.f * Run - Ru;
        v2f Rdb = 2.f * Rdn - Rd;
        P = Pn; Ru = Run; Rd = Rdn;

        // ---- per-half sums over generators ----
        float sP  = Pb.x  + Pb.y;
        float sRu = Rub.x + Rub.y;
        float sRd = Rdb.x + Rdb.y;
        half_sum3(sP, sRu, sRd);

        // ---- z-update: z += tau*sigma*(K x_bar - q), clamp ineq rows ----
        z0  = z0 + ts * sP - tsf;                         // equality row
        z1  = vmax0(z1 + ts * (Pb + Rub) - tspmx);        // P+Ru <= pmax
        z2  = vmax0(z2 + ts * (Rdb - Pb) + tspmn);        // -P+Rd <= -pmin
        z3  = vmax0(z3 + ts * Pb - tspmx);                // P <= pmax
        z4  = vmax0(z4 - ts * Pb + tspmn);                // -P <= -pmin
        zru = fmaxf(zru + tsreq - ts * sRu, 0.f);         // -sum Ru <= -req
        zrd = fmaxf(zrd + tsreq - ts * sRd, 0.f);         // -sum Rd <= -req
    }

    const v2f cost = bj * P + cj;
    {
        const int base0 = b * (G * T) + g0 * T + t;       // (B,G,T) index
        out[base0]              = P.x;
        out[SZ + base0]         = Ru.x;
        out[2 * SZ + base0]     = Rd.x;
        out[3 * SZ + B + base0] = cost.x;
        if (a1) {
            const int base1 = b * (G * T) + g1 * T + t;
            out[base1]              = P.y;
            out[SZ + base1]         = Ru.y;
            out[2 * SZ + base1]     = Rd.y;
            out[3 * SZ + B + base1] = cost.y;
        }
    }

    if (ws_partial) {
        // per-(b,t) objective partial: sum_g cost + 0.05*b*Ru + 0.02*b*Rd
        v2f lo2 = cost + (0.05f * bj) * Ru + (0.02f * bj) * Rd;
        float tot = half_sum1(lo2.x + lo2.y);
        if (lh == 0) ws_partial[lp] = tot;
    }
}

// obj[b] = sum_t ws_partial[b*T + t]   (deterministic, tiny)
__global__ __launch_bounds__(64)
void obj_final_kernel(const float* __restrict__ ws_partial, float* __restrict__ out)
{
    const int b = blockIdx.x * 64 + threadIdx.x;
    if (b < B) {
        float s = 0.f;
        #pragma unroll
        for (int t = 0; t < T; ++t) s += ws_partial[b * T + t];
        out[3 * SZ + b] = s;
    }
}

// Fallback (ws too small): recompute obj from outputs, one block per b
__global__ __launch_bounds__(256)
void obj_kernel(const float* __restrict__ bcost, float* __restrict__ out)
{
    const int b = blockIdx.x;
    const float* Ru = out + SZ     + (size_t)b * (G * T);
    const float* Rd = out + 2 * SZ + (size_t)b * (G * T);
    const float* C  = out + 3 * SZ + B + (size_t)b * (G * T);

    float s = 0.f;
    for (int i = threadIdx.x; i < G * T; i += 256) {
        const int g = i / T;
        const float bg = bcost[g];
        s += C[i] + 0.05f * bg * Ru[i] + 0.02f * bg * Rd[i];
    }
    __shared__ float sm[4];
    s = wave_sum1(s);
    if ((threadIdx.x & 63) == 0) sm[threadIdx.x >> 6] = s;
    __syncthreads();
    if (threadIdx.x == 0) out[3 * SZ + b] = (sm[0] + sm[1]) + (sm[2] + sm[3]);
}

extern "C" void kernel_launch(void* const* d_in, const int* in_sizes, int n_in,
                              void* d_out, int out_size, void* d_ws, size_t ws_size,
                              hipStream_t stream) {
    const float* forecast = (const float*)d_in[0];
    const float* pmin_p   = (const float*)d_in[1];
    const float* pmax_p   = (const float*)d_in[2];
    const float* b_p      = (const float*)d_in[3];
    const float* c_p      = (const float*)d_in[4];
    const int*   niter_p  = (const int*)  d_in[5];
    float* out = (float*)d_out;

    // ||K||_2 analytic for this fixed 0/±1 structure (G=50):
    // K^T K = [[4I+J, I, -I],[I, I+J, 0],[-I, 0, I+J]]; largest eig on the
    // ones-subspace is (105+sqrt(17))/2  ->  L = sqrt((105+sqrt(17))/2)
    const double L = sqrt((105.0 + sqrt(17.0)) * 0.5);
    const float tau = (float)(0.9 / L);   // sigma == tau

    const bool use_ws = (ws_size >= (size_t)NLP * sizeof(float));
    float* wsp = use_ws ? (float*)d_ws : nullptr;

    pdhg_lp_kernel<<<NLP / 2, 64, 0, stream>>>(forecast, pmin_p, pmax_p,
                                               b_p, c_p, niter_p, out, wsp, tau);
    if (use_ws) {
        obj_final_kernel<<<(B + 63) / 64, 64, 0, stream>>>(wsp, out);
    } else {
        obj_kernel<<<B, 256, 0, stream>>>(b_p, out);
    }
}

// Round 4
// 137.894 us; speedup vs baseline: 1.8084x; 1.0671x over previous
//
#include <hip/hip_runtime.h>
#include <math.h>

#define G   50
#define T   24
#define B   128
#define NLP (B * T)
#define SZ  (B * G * T)   // 153600 elements per (B,G,T) output

typedef float v2f __attribute__((ext_vector_type(2)));

// d_out layout (floats, concatenated in return order):
//   [0,      SZ)        P_DA   (B,G,T)
//   [SZ,     2SZ)       R_up
//   [2SZ,    3SZ)       R_dn
//   [3SZ,    3SZ+B)     obj    (B,)
//   [3SZ+B,  4SZ+B)     Cost_DA

__device__ __forceinline__ v2f vmax0(v2f v) {
    v2f z = {0.f, 0.f};
    return __builtin_elementwise_max(v, z);
}

// DPP helper: result = src lane per CTRL (row ops), all rows/banks enabled.
template <int CTRL>
__device__ __forceinline__ float dpp_mov(float x) {
    int r = __builtin_amdgcn_update_dpp(0, __float_as_int(x), CTRL, 0xf, 0xf, true);
    return __int_as_float(r);
}

// All-reduce 3 values within each 16-lane ROW independently (pure DPP/VALU):
// row_ror:1,2,4,8 rotate-reduce -> every lane of the row holds the row sum.
__device__ __forceinline__ void row_sum3(float& a, float& b, float& c) {
    a += dpp_mov<0x121>(a); b += dpp_mov<0x121>(b); c += dpp_mov<0x121>(c); // ror:1
    a += dpp_mov<0x122>(a); b += dpp_mov<0x122>(b); c += dpp_mov<0x122>(c); // ror:2
    a += dpp_mov<0x124>(a); b += dpp_mov<0x124>(b); c += dpp_mov<0x124>(c); // ror:4
    a += dpp_mov<0x128>(a); b += dpp_mov<0x128>(b); c += dpp_mov<0x128>(c); // ror:8
}

__device__ __forceinline__ float row_sum1(float a) {
    a += dpp_mov<0x121>(a);
    a += dpp_mov<0x122>(a);
    a += dpp_mov<0x124>(a);
    a += dpp_mov<0x128>(a);
    return a;
}

// One wave per block; row r = lane>>4 (16 lanes) solves LP (4*blockIdx + r).
// Each lane owns generators {lh, lh+16, lh+32, lh+48} packed as two v2f
// (A = {lh, lh+16} always valid; B = {lh+32, lh+48}, .y valid iff lh<2).
__global__ __launch_bounds__(64)
void pdhg_lp_kernel(const float* __restrict__ forecast,
                    const float* __restrict__ pmin,
                    const float* __restrict__ pmax,
                    const float* __restrict__ bcost,
                    const float* __restrict__ ccost,
                    const int*   __restrict__ n_iters_p,
                    float* __restrict__ out,
                    float* __restrict__ ws_partial,   // NLP floats (or null)
                    float tau)
{
    const int lane = threadIdx.x;         // 0..63
    const int lh   = lane & 15;           // lane within row
    const int row  = lane >> 4;           // LP slot within wave
    const int lp   = blockIdx.x * 4 + row;
    const int b    = lp / T;
    const int t    = lp - b * T;
    const int n_iters = n_iters_p[0];

    const int  gA0 = lh,      gA1 = lh + 16;   // always < 50
    const int  gB0 = lh + 32;                  // always < 50 (<=47)
    const int  gB1 = lh + 48;                  // valid iff lh < 2
    const bool vB1 = (lh < 2);

    v2f bjA  = { bcost[gA0], bcost[gA1] };
    v2f bjB  = { bcost[gB0], vB1 ? bcost[gB1] : 0.f };
    v2f cjA  = { ccost[gA0], ccost[gA1] };
    v2f cjB  = { ccost[gB0], vB1 ? ccost[gB1] : 0.f };
    v2f pmxA = { pmax[gA0],  pmax[gA1] };
    v2f pmxB = { pmax[gB0],  vB1 ? pmax[gB1] : 0.f };
    v2f pmnA = { pmin[gA0],  pmin[gA1] };
    v2f pmnB = { pmin[gB0],  vB1 ? pmin[gB1] : 0.f };
    const float f = forecast[lp];         // uniform within each row

    const float ts  = tau * tau;          // sigma == tau
    const float BIG = 1e30f;              // sentinel: clamps invalid slot to 0

    v2f tcPA  = tau * bjA;
    v2f tcPB  = tau * bjB;           if (!vB1) tcPB.y  = BIG;
    v2f tcRuA = (tau * 0.05f) * bjA;
    v2f tcRuB = (tau * 0.05f) * bjB; if (!vB1) tcRuB.y = BIG;
    v2f tcRdA = (tau * 0.02f) * bjA;
    v2f tcRdB = (tau * 0.02f) * bjB; if (!vB1) tcRdB.y = BIG;
    v2f tspmxA = ts * pmxA, tspmxB = ts * pmxB;
    v2f tspmnA = ts * pmnA, tspmnB = ts * pmnB;
    const float tsf   = ts * f;
    const float tsreq = ts * 0.02f * f;   // REQ_UP_RATIO == REQ_DN_RATIO

    v2f PA = {0,0}, PB = {0,0}, RuA = {0,0}, RuB = {0,0}, RdA = {0,0}, RdB = {0,0};
    v2f z1A = {0,0}, z1B = {0,0}, z2A = {0,0}, z2B = {0,0};
    v2f z3A = {0,0}, z3B = {0,0}, z4A = {0,0}, z4B = {0,0};   // scaled duals tau*y
    float z0 = 0.f, zru = 0.f, zrd = 0.f;                     // row-uniform

    for (int it = 0; it < n_iters; ++it) {
        // ---- x-update: x_new = max(x - (tau*c + tau*K^T y), 0) ----
        v2f z0v = { z0, z0 };
        v2f zruv = { zru, zru };
        v2f zrdv = { zrd, zrd };
        v2f gPA = (z1A - z2A) + (z3A - z4A) + z0v;
        v2f gPB = (z1B - z2B) + (z3B - z4B) + z0v;
        v2f PnA = vmax0(PA - tcPA - gPA);
        v2f PnB = vmax0(PB - tcPB - gPB);
        v2f RunA = vmax0(RuA - tcRuA - z1A + zruv);
        v2f RunB = vmax0(RuB - tcRuB - z1B + zruv);
        v2f RdnA = vmax0(RdA - tcRdA - z2A + zrdv);
        v2f RdnB = vmax0(RdB - tcRdB - z2B + zrdv);

        // overrelaxation: x_bar = 2*x_new - x_old
        v2f PbA  = 2.f * PnA  - PA,  PbB  = 2.f * PnB  - PB;
        v2f RubA = 2.f * RunA - RuA, RubB = 2.f * RunB - RuB;
        v2f RdbA = 2.f * RdnA - RdA, RdbB = 2.f * RdnB - RdB;
        PA = PnA; PB = PnB; RuA = RunA; RuB = RunB; RdA = RdnA; RdB = RdnB;

        // ---- row-local sums over generators (pure DPP, no LDS) ----
        v2f tP = PbA + PbB, tRu = RubA + RubB, tRd = RdbA + RdbB;
        float sP  = tP.x  + tP.y;
        float sRu = tRu.x + tRu.y;
        float sRd = tRd.x + tRd.y;
        row_sum3(sP, sRu, sRd);

        // ---- z-update: z += tau*sigma*(K x_bar - q), clamp ineq rows ----
        z0  = z0 + ts * sP - tsf;                             // equality row
        z1A = vmax0(z1A + ts * (PbA + RubA) - tspmxA);        // P+Ru <= pmax
        z1B = vmax0(z1B + ts * (PbB + RubB) - tspmxB);
        z2A = vmax0(z2A + ts * (RdbA - PbA) + tspmnA);        // -P+Rd <= -pmin
        z2B = vmax0(z2B + ts * (RdbB - PbB) + tspmnB);
        z3A = vmax0(z3A + ts * PbA - tspmxA);                 // P <= pmax
        z3B = vmax0(z3B + ts * PbB - tspmxB);
        z4A = vmax0(z4A - ts * PbA + tspmnA);                 // -P <= -pmin
        z4B = vmax0(z4B - ts * PbB + tspmnB);
        zru = fmaxf(zru + tsreq - ts * sRu, 0.f);             // -sum Ru <= -req
        zrd = fmaxf(zrd + tsreq - ts * sRd, 0.f);             // -sum Rd <= -req
    }

    const v2f costA = bjA * PA + cjA;
    const v2f costB = bjB * PB + cjB;
    {
        const int bgt = b * (G * T) + t;
        const int a0 = bgt + gA0 * T, a1 = bgt + gA1 * T, b0 = bgt + gB0 * T;
        out[a0] = PA.x;  out[SZ + a0] = RuA.x;  out[2*SZ + a0] = RdA.x;  out[3*SZ + B + a0] = costA.x;
        out[a1] = PA.y;  out[SZ + a1] = RuA.y;  out[2*SZ + a1] = RdA.y;  out[3*SZ + B + a1] = costA.y;
        out[b0] = PB.x;  out[SZ + b0] = RuB.x;  out[2*SZ + b0] = RdB.x;  out[3*SZ + B + b0] = costB.x;
        if (vB1) {
            const int b1 = bgt + gB1 * T;
            out[b1] = PB.y;  out[SZ + b1] = RuB.y;  out[2*SZ + b1] = RdB.y;  out[3*SZ + B + b1] = costB.y;
        }
    }

    if (ws_partial) {
        // per-(b,t) objective partial: sum_g cost + 0.05*b*Ru + 0.02*b*Rd
        v2f lo = costA + (0.05f * bjA) * RuA + (0.02f * bjA) * RdA
               + costB + (0.05f * bjB) * RuB + (0.02f * bjB) * RdB;
        float tot = row_sum1(lo.x + lo.y);
        if (lh == 0) ws_partial[lp] = tot;
    }
}

// obj[b] = sum_t ws_partial[b*T + t]   (deterministic, tiny)
__global__ __launch_bounds__(64)
void obj_final_kernel(const float* __restrict__ ws_partial, float* __restrict__ out)
{
    const int b = blockIdx.x * 64 + threadIdx.x;
    if (b < B) {
        float s = 0.f;
        #pragma unroll
        for (int t = 0; t < T; ++t) s += ws_partial[b * T + t];
        out[3 * SZ + b] = s;
    }
}

// Fallback (ws too small): recompute obj from outputs, one block per b
__global__ __launch_bounds__(256)
void obj_kernel(const float* __restrict__ bcost, float* __restrict__ out)
{
    const int b = blockIdx.x;
    const float* Ru = out + SZ     + (size_t)b * (G * T);
    const float* Rd = out + 2 * SZ + (size_t)b * (G * T);
    const float* C  = out + 3 * SZ + B + (size_t)b * (G * T);

    float s = 0.f;
    for (int i = threadIdx.x; i < G * T; i += 256) {
        const int g = i / T;
        const float bg = bcost[g];
        s += C[i] + 0.05f * bg * Ru[i] + 0.02f * bg * Rd[i];
    }
    __shared__ float sm[16];
    s = row_sum1(s);                                 // 16-lane row sums
    if ((threadIdx.x & 15) == 0) sm[threadIdx.x >> 4] = s;
    __syncthreads();
    if (threadIdx.x == 0) {
        float tot = 0.f;
        #pragma unroll
        for (int i = 0; i < 16; ++i) tot += sm[i];
        out[3 * SZ + b] = tot;
    }
}

extern "C" void kernel_launch(void* const* d_in, const int* in_sizes, int n_in,
                              void* d_out, int out_size, void* d_ws, size_t ws_size,
                              hipStream_t stream) {
    const float* forecast = (const float*)d_in[0];
    const float* pmin_p   = (const float*)d_in[1];
    const float* pmax_p   = (const float*)d_in[2];
    const float* b_p      = (const float*)d_in[3];
    const float* c_p      = (const float*)d_in[4];
    const int*   niter_p  = (const int*)  d_in[5];
    float* out = (float*)d_out;

    // ||K||_2 analytic for this fixed 0/±1 structure (G=50):
    // K^T K = [[4I+J, I, -I],[I, I+J, 0],[-I, 0, I+J]]; largest eig on the
    // ones-subspace is (105+sqrt(17))/2  ->  L = sqrt((105+sqrt(17))/2)
    const double L = sqrt((105.0 + sqrt(17.0)) * 0.5);
    const float tau = (float)(0.9 / L);   // sigma == tau

    const bool use_ws = (ws_size >= (size_t)NLP * sizeof(float));
    float* wsp = use_ws ? (float*)d_ws : nullptr;

    pdhg_lp_kernel<<<NLP / 4, 64, 0, stream>>>(forecast, pmin_p, pmax_p,
                                               b_p, c_p, niter_p, out, wsp, tau);
    if (use_ws) {
        obj_final_kernel<<<(B + 63) / 64, 64, 0, stream>>>(wsp, out);
    } else {
        obj_kernel<<<B, 256, 0, stream>>>(b_p, out);
    }
}